// Round 4
// baseline (273.113 us; speedup 1.0000x reference)
//
#include <hip/hip_runtime.h>

// QKBmm: out[b,m,q,kv] = sum_h q[b,m,q,h] * k[b,m,kv,h]
// B=2, M=16, QT=1024, KVT=4096, H=128. fp32 in/out, bf16 MFMA compute.
// Write-bound: 512 MB out + ~84 MB compulsory reads -> ~91us floor @6.7TB/s.
// R2: NT stores + XCD swizzle (195->136us).
// R3 FAILED: float4 NT epilogue regressed (136->154) — 16-line-span stores
//     hotspot L2 channels. Reverted to R2's scalar-dword epilogue.
// R4: drop LDS staging entirely — K=128 fits in registers. Fragments loaded
//     global->reg (L2-served, 16 full 128B lines/instr), fp32->bf16 cvt
//     in-reg. NO barriers, NO LDS -> waves free-run, continuous read+write
//     interleave instead of barrier-coupled bursts at 2 blocks/CU.

#define QT   1024
#define KVT  4096
#define HD   128
#define NXCD 8

using bf16x8 = __attribute__((ext_vector_type(8))) __bf16;
using f32x4  = __attribute__((ext_vector_type(4))) float;

__global__ __launch_bounds__(256, 3)
void QKBmm_74062416052397_kernel(const float* __restrict__ q,
                                 const float* __restrict__ k,
                                 float* __restrict__ out) {
    const int t = threadIdx.x;         // 0..255

    // XCD-aware remap: 8192 blocks, 1024 contiguous per XCD (bijective: 8192%8==0).
    // Within a chunk: n fastest (q-tile reuse x32), then m (k-slice 2.1MB < 4MB L2).
    const unsigned lin = blockIdx.x;
    const unsigned swz = (lin & (NXCD - 1)) * (8192u / NXCD) + (lin >> 3);
    const int nt_ = swz & 31;          // KV tile index (fastest)
    const int mt  = (swz >> 5) & 7;    // Q tile index
    const int bm  = swz >> 8;          // batch*M index
    const int m0  = mt * 128;
    const int n0  = nt_ * 128;

    const int lane = t & 63;
    const int wid  = t >> 6;
    const int wm   = (wid >> 1) * 64;  // wave row offset within tile
    const int wn   = (wid & 1) * 64;   // wave col offset within tile
    const int lr   = lane & 15;        // fragment row index
    const int lg   = lane >> 4;        // k-group 0..3

    // Per-lane row bases: lane (lr,lg) reads rows base+mi*16 / +ni*16,
    // fp32 cols kc..kc+7 where kc = ks*32 + lg*8.
    const float* __restrict__ Qb = q + ((size_t)bm * QT  + m0 + wm + lr) * HD;
    const float* __restrict__ Kb = k + ((size_t)bm * KVT + n0 + wn + lr) * HD;

    f32x4 acc[4][4] = {};              // [mi][ni]

#pragma unroll
    for (int ks = 0; ks < 4; ++ks) {
        const int kc = ks * 32 + lg * 8;
        bf16x8 bfr[4];
#pragma unroll
        for (int ni = 0; ni < 4; ++ni) {
            const float* p = Kb + ni * 16 * HD + kc;
            float4 u0 = *reinterpret_cast<const float4*>(p);
            float4 u1 = *reinterpret_cast<const float4*>(p + 4);
            bfr[ni] = bf16x8{ (__bf16)u0.x, (__bf16)u0.y, (__bf16)u0.z, (__bf16)u0.w,
                              (__bf16)u1.x, (__bf16)u1.y, (__bf16)u1.z, (__bf16)u1.w };
        }
#pragma unroll
        for (int mi = 0; mi < 4; ++mi) {
            const float* p = Qb + mi * 16 * HD + kc;
            float4 u0 = *reinterpret_cast<const float4*>(p);
            float4 u1 = *reinterpret_cast<const float4*>(p + 4);
            bf16x8 af = { (__bf16)u0.x, (__bf16)u0.y, (__bf16)u0.z, (__bf16)u0.w,
                          (__bf16)u1.x, (__bf16)u1.y, (__bf16)u1.z, (__bf16)u1.w };
#pragma unroll
            for (int ni = 0; ni < 4; ++ni)
                acc[mi][ni] = __builtin_amdgcn_mfma_f32_16x16x32_bf16(
                    af, bfr[ni], acc[mi][ni], 0, 0, 0);
        }
    }

    // ---- Epilogue: EXACT R2 layout (proven fastest). C/D map:
    //      row = lg*4 + j, col = lr within each 16x16. Scalar NT dwords:
    //      one instr = 4 rows x 64B segments; adjacent ni-instrs complete lines.
    float* __restrict__ Cp = out + (size_t)bm * QT * KVT;
#pragma unroll
    for (int mi = 0; mi < 4; ++mi) {
#pragma unroll
        for (int j = 0; j < 4; ++j) {
            int row = m0 + wm + mi * 16 + lg * 4 + j;
            float* rp = Cp + (size_t)row * KVT + n0 + wn;
#pragma unroll
            for (int ni = 0; ni < 4; ++ni)
                __builtin_nontemporal_store(acc[mi][ni][j], rp + ni * 16 + lr);
        }
    }
}

extern "C" void kernel_launch(void* const* d_in, const int* in_sizes, int n_in,
                              void* d_out, int out_size, void* d_ws, size_t ws_size,
                              hipStream_t stream) {
    const float* q = (const float*)d_in[0];
    const float* k = (const float*)d_in[1];
    float* out = (float*)d_out;

    QKBmm_74062416052397_kernel<<<dim3(8192), dim3(256), 0, stream>>>(q, k, out);
}

// Round 5
// 134.698 us; speedup vs baseline: 2.0276x; 2.0276x over previous
//
#include <hip/hip_runtime.h>

// QKBmm: out[b,m,q,kv] = sum_h q[b,m,q,h] * k[b,m,kv,h]
// B=2, M=16, QT=1024, KVT=4096, H=128. fp32 in/out, bf16 MFMA compute.
// Write-bound: 512 MB out; inputs are L3-resident (R4 profile: FETCH ~45MB).
// R2: LDS-staged 128x128 tile, NT scalar-dword stores + XCD swizzle -> 136us.
// R3 FAILED: float4 NT epilogue (136->154) — wide-span stores hotspot L2.
// R4 FAILED: no-LDS reg fragments (273us) — latency-bound, L1 request-heavy.
// R5: R2 + K-split double-buffer (T14 issue-early/write-late) to hide the
//     ~30us L2-served staging under MFMA compute. Everything else = R2.

#define QT   1024
#define KVT  4096
#define HD   128
#define NXCD 8

using bf16x8 = __attribute__((ext_vector_type(8))) __bf16;
using bf16x4 = __attribute__((ext_vector_type(4))) __bf16;
using f32x4  = __attribute__((ext_vector_type(4))) float;

__global__ __launch_bounds__(256, 2)
void QKBmm_74062416052397_kernel(const float* __restrict__ q,
                                 const float* __restrict__ k,
                                 float* __restrict__ out) {
    // Two 128x64 bf16 half-K buffers per input (16KB each, 64KB total).
    __shared__ __bf16 As[2][128 * 64];
    __shared__ __bf16 Bs[2][128 * 64];

    const int t = threadIdx.x;         // 0..255

    // XCD-aware remap (bijective, 8192%8==0): n fastest (q reuse), then m.
    const unsigned lin = blockIdx.x;
    const unsigned swz = (lin & (NXCD - 1)) * (8192u / NXCD) + (lin >> 3);
    const int nt_ = swz & 31;          // KV tile index (fastest)
    const int mt  = (swz >> 5) & 7;    // Q tile index
    const int bm  = swz >> 8;          // batch*M index
    const int m0  = mt * 128;
    const int n0  = nt_ * 128;

    const float4* __restrict__ Q4 =
        reinterpret_cast<const float4*>(q + ((size_t)bm * QT  + m0) * HD);
    const float4* __restrict__ K4 =
        reinterpret_cast<const float4*>(k + ((size_t)bm * KVT + n0) * HD);

    // Staging geometry (per half): 128 rows x 16 float4; thread does 8 each.
    // f = it*256 + t; row = f>>4; c4 = f&15; global f4 idx = row*32 + h*16 + c4.
    // LDS elem e = (row*64 + c4*4) ^ ((row&7)<<3)  (XOR swizzle, 16B units).

    // ---- Phase A: stage half 0 ----
    float4 qa[8], ka[8];
#pragma unroll
    for (int it = 0; it < 8; ++it) {
        int f = it * 256 + t, row = f >> 4, c4 = f & 15;
        qa[it] = Q4[row * 32 + c4];
        ka[it] = K4[row * 32 + c4];
    }
#pragma unroll
    for (int it = 0; it < 8; ++it) {
        int f = it * 256 + t, row = f >> 4, c4 = f & 15;
        int e = (row * 64 + c4 * 4) ^ ((row & 7) << 3);
        float4 va = qa[it], vb = ka[it];
        *reinterpret_cast<bf16x4*>(&As[0][e]) =
            bf16x4{ (__bf16)va.x, (__bf16)va.y, (__bf16)va.z, (__bf16)va.w };
        *reinterpret_cast<bf16x4*>(&Bs[0][e]) =
            bf16x4{ (__bf16)vb.x, (__bf16)vb.y, (__bf16)vb.z, (__bf16)vb.w };
    }
    __syncthreads();

    const int lane = t & 63;
    const int wid  = t >> 6;
    const int wm   = (wid >> 1) * 64;  // wave row offset within tile
    const int wn   = (wid & 1) * 64;   // wave col offset within tile
    const int lr   = lane & 15;        // fragment row index
    const int lg   = lane >> 4;        // k-group 0..3

    f32x4 acc[4][4] = {};              // [mi][ni]

    // ---- Phase B: issue half-1 loads (AFTER barrier, so no drain stall),
    //      compute ks0-1 from buf0 under the load latency, then write buf1.
    float4 qb[8], kb[8];
#pragma unroll
    for (int it = 0; it < 8; ++it) {
        int f = it * 256 + t, row = f >> 4, c4 = f & 15;
        qb[it] = Q4[row * 32 + 16 + c4];
        kb[it] = K4[row * 32 + 16 + c4];
    }

#pragma unroll
    for (int ks = 0; ks < 2; ++ks) {
        const int kcol = ks * 32 + lg * 8;
        bf16x8 af[4], bfr[4];
#pragma unroll
        for (int mi = 0; mi < 4; ++mi) {
            int r = wm + mi * 16 + lr;
            int e = (r * 64 + kcol) ^ ((r & 7) << 3);
            af[mi] = *reinterpret_cast<const bf16x8*>(&As[0][e]);
        }
#pragma unroll
        for (int ni = 0; ni < 4; ++ni) {
            int r = wn + ni * 16 + lr;
            int e = (r * 64 + kcol) ^ ((r & 7) << 3);
            bfr[ni] = *reinterpret_cast<const bf16x8*>(&Bs[0][e]);
        }
#pragma unroll
        for (int mi = 0; mi < 4; ++mi)
#pragma unroll
            for (int ni = 0; ni < 4; ++ni)
                acc[mi][ni] = __builtin_amdgcn_mfma_f32_16x16x32_bf16(
                    af[mi], bfr[ni], acc[mi][ni], 0, 0, 0);
    }

    // cvt + write half 1 (forces vmcnt wait only here, after 32 MFMAs)
#pragma unroll
    for (int it = 0; it < 8; ++it) {
        int f = it * 256 + t, row = f >> 4, c4 = f & 15;
        int e = (row * 64 + c4 * 4) ^ ((row & 7) << 3);
        float4 va = qb[it], vb = kb[it];
        *reinterpret_cast<bf16x4*>(&As[1][e]) =
            bf16x4{ (__bf16)va.x, (__bf16)va.y, (__bf16)va.z, (__bf16)va.w };
        *reinterpret_cast<bf16x4*>(&Bs[1][e]) =
            bf16x4{ (__bf16)vb.x, (__bf16)vb.y, (__bf16)vb.z, (__bf16)vb.w };
    }
    __syncthreads();

    // ---- Phase C: compute ks2-3 from buf1 ----
#pragma unroll
    for (int ks = 0; ks < 2; ++ks) {
        const int kcol = ks * 32 + lg * 8;
        bf16x8 af[4], bfr[4];
#pragma unroll
        for (int mi = 0; mi < 4; ++mi) {
            int r = wm + mi * 16 + lr;
            int e = (r * 64 + kcol) ^ ((r & 7) << 3);
            af[mi] = *reinterpret_cast<const bf16x8*>(&As[1][e]);
        }
#pragma unroll
        for (int ni = 0; ni < 4; ++ni) {
            int r = wn + ni * 16 + lr;
            int e = (r * 64 + kcol) ^ ((r & 7) << 3);
            bfr[ni] = *reinterpret_cast<const bf16x8*>(&Bs[1][e]);
        }
#pragma unroll
        for (int mi = 0; mi < 4; ++mi)
#pragma unroll
            for (int ni = 0; ni < 4; ++ni)
                acc[mi][ni] = __builtin_amdgcn_mfma_f32_16x16x32_bf16(
                    af[mi], bfr[ni], acc[mi][ni], 0, 0, 0);
    }

    // ---- Epilogue: EXACT R2 layout (proven fastest). Scalar NT dwords:
    //      one instr = 4 rows x 64B segments; adjacent ni-instrs complete lines.
    float* __restrict__ Cp = out + (size_t)bm * QT * KVT;
#pragma unroll
    for (int mi = 0; mi < 4; ++mi) {
#pragma unroll
        for (int j = 0; j < 4; ++j) {
            int row = m0 + wm + mi * 16 + lg * 4 + j;
            float* rp = Cp + (size_t)row * KVT + n0 + wn;
#pragma unroll
            for (int ni = 0; ni < 4; ++ni)
                __builtin_nontemporal_store(acc[mi][ni][j], rp + ni * 16 + lr);
        }
    }
}

extern "C" void kernel_launch(void* const* d_in, const int* in_sizes, int n_in,
                              void* d_out, int out_size, void* d_ws, size_t ws_size,
                              hipStream_t stream) {
    const float* q = (const float*)d_in[0];
    const float* k = (const float*)d_in[1];
    float* out = (float*)d_out;

    QKBmm_74062416052397_kernel<<<dim3(8192), dim3(256), 0, stream>>>(q, k, out);
}

// Round 6
// 122.582 us; speedup vs baseline: 2.2280x; 1.0988x over previous
//
#include <hip/hip_runtime.h>

// QKBmm: out[b,m,q,kv] = sum_h q[b,m,q,h] * k[b,m,kv,h]
// B=2, M=16, QT=1024, KVT=4096, H=128. fp32 in/out, bf16 MFMA compute.
// Write-bound: 512 MB out; inputs are L3/L2-resident (FETCH ~45MB).
// R2: LDS-staged 128x128 tile, NT scalar-dword stores + XCD swizzle -> 136us.
// R3 FAILED: float4 NT epilogue (136->154) — wide-span stores hotspot L2.
// R4 FAILED: no-LDS reg fragments (273us) — latency-bound.
// R5 NEUTRAL: intra-block K-split dbuf (134.7us) — staging wasn't the cost.
// R6: occupancy 2->4 blocks/CU (32KB LDS single-half buffer, lb(256,4)) so
//     epilogue write-bursts from staggered blocks interleave -> smooth the
//     HBM write stream (observed 4.3 TB/s vs 6.7 pure-write ceiling).

#define QT   1024
#define KVT  4096
#define HD   128
#define NXCD 8

using bf16x8 = __attribute__((ext_vector_type(8))) __bf16;
using bf16x4 = __attribute__((ext_vector_type(4))) __bf16;
using f32x4  = __attribute__((ext_vector_type(4))) float;

__global__ __launch_bounds__(256, 4)
void QKBmm_74062416052397_kernel(const float* __restrict__ q,
                                 const float* __restrict__ k,
                                 float* __restrict__ out) {
    // Single 128x64 bf16 half-K buffer per input (16KB each, 32KB total).
    __shared__ __bf16 As[128 * 64];
    __shared__ __bf16 Bs[128 * 64];

    const int t = threadIdx.x;         // 0..255

    // XCD-aware remap (bijective, 8192%8==0): n fastest (q reuse), then m.
    const unsigned lin = blockIdx.x;
    const unsigned swz = (lin & (NXCD - 1)) * (8192u / NXCD) + (lin >> 3);
    const int nt_ = swz & 31;          // KV tile index (fastest)
    const int mt  = (swz >> 5) & 7;    // Q tile index
    const int bm  = swz >> 8;          // batch*M index
    const int m0  = mt * 128;
    const int n0  = nt_ * 128;

    const float4* __restrict__ Q4 =
        reinterpret_cast<const float4*>(q + ((size_t)bm * QT  + m0) * HD);
    const float4* __restrict__ K4 =
        reinterpret_cast<const float4*>(k + ((size_t)bm * KVT + n0) * HD);

    const int lane = t & 63;
    const int wid  = t >> 6;
    const int wm   = (wid >> 1) * 64;  // wave row offset within tile
    const int wn   = (wid & 1) * 64;   // wave col offset within tile
    const int lr   = lane & 15;        // fragment row index
    const int lg   = lane >> 4;        // k-group 0..3

    f32x4 acc[4][4] = {};              // [mi][ni]

    // Staging geometry (per half): 128 rows x 16 float4; thread does 8 each.
    // f = it*256 + t; row = f>>4; c4 = f&15; global f4 idx = row*32 + h*16 + c4.
    // LDS elem e = (row*64 + c4*4) ^ ((row&7)<<3)  (XOR swizzle, 16B units).
#pragma unroll
    for (int h = 0; h < 2; ++h) {
        if (h) __syncthreads();        // prior compute done reading the buffer

        // ---- Stage half h (8-deep float4 batches; ~32 VGPR transient) ----
        float4 qv[4], kv[4];
#pragma unroll
        for (int it = 0; it < 4; ++it) {
            int f = it * 256 + t, row = f >> 4, c4 = f & 15;
            qv[it] = Q4[row * 32 + h * 16 + c4];
            kv[it] = K4[row * 32 + h * 16 + c4];
        }
#pragma unroll
        for (int it = 0; it < 4; ++it) {
            int f = it * 256 + t, row = f >> 4, c4 = f & 15;
            int e = (row * 64 + c4 * 4) ^ ((row & 7) << 3);
            *reinterpret_cast<bf16x4*>(&As[e]) =
                bf16x4{ (__bf16)qv[it].x, (__bf16)qv[it].y, (__bf16)qv[it].z, (__bf16)qv[it].w };
            *reinterpret_cast<bf16x4*>(&Bs[e]) =
                bf16x4{ (__bf16)kv[it].x, (__bf16)kv[it].y, (__bf16)kv[it].z, (__bf16)kv[it].w };
        }
#pragma unroll
        for (int it = 4; it < 8; ++it) {
            int f = it * 256 + t, row = f >> 4, c4 = f & 15;
            qv[it - 4] = Q4[row * 32 + h * 16 + c4];
            kv[it - 4] = K4[row * 32 + h * 16 + c4];
        }
#pragma unroll
        for (int it = 4; it < 8; ++it) {
            int f = it * 256 + t, row = f >> 4, c4 = f & 15;
            int e = (row * 64 + c4 * 4) ^ ((row & 7) << 3);
            *reinterpret_cast<bf16x4*>(&As[e]) =
                bf16x4{ (__bf16)qv[it-4].x, (__bf16)qv[it-4].y, (__bf16)qv[it-4].z, (__bf16)qv[it-4].w };
            *reinterpret_cast<bf16x4*>(&Bs[e]) =
                bf16x4{ (__bf16)kv[it-4].x, (__bf16)kv[it-4].y, (__bf16)kv[it-4].z, (__bf16)kv[it-4].w };
        }
        __syncthreads();

        // ---- Compute 2 K-steps from the staged half ----
#pragma unroll
        for (int ks = 0; ks < 2; ++ks) {
            const int kcol = ks * 32 + lg * 8;
            bf16x8 af[4], bfr[4];
#pragma unroll
            for (int mi = 0; mi < 4; ++mi) {
                int r = wm + mi * 16 + lr;
                int e = (r * 64 + kcol) ^ ((r & 7) << 3);
                af[mi] = *reinterpret_cast<const bf16x8*>(&As[e]);
            }
#pragma unroll
            for (int ni = 0; ni < 4; ++ni) {
                int r = wn + ni * 16 + lr;
                int e = (r * 64 + kcol) ^ ((r & 7) << 3);
                bfr[ni] = *reinterpret_cast<const bf16x8*>(&Bs[e]);
            }
#pragma unroll
            for (int mi = 0; mi < 4; ++mi)
#pragma unroll
                for (int ni = 0; ni < 4; ++ni)
                    acc[mi][ni] = __builtin_amdgcn_mfma_f32_16x16x32_bf16(
                        af[mi], bfr[ni], acc[mi][ni], 0, 0, 0);
        }
    }

    // ---- Epilogue: EXACT R2 layout (proven fastest). Scalar NT dwords:
    //      one instr = 4 rows x 64B segments; adjacent ni-instrs complete lines.
    float* __restrict__ Cp = out + (size_t)bm * QT * KVT;
#pragma unroll
    for (int mi = 0; mi < 4; ++mi) {
#pragma unroll
        for (int j = 0; j < 4; ++j) {
            int row = m0 + wm + mi * 16 + lg * 4 + j;
            float* rp = Cp + (size_t)row * KVT + n0 + wn;
#pragma unroll
            for (int ni = 0; ni < 4; ++ni)
                __builtin_nontemporal_store(acc[mi][ni][j], rp + ni * 16 + lr);
        }
    }
}

extern "C" void kernel_launch(void* const* d_in, const int* in_sizes, int n_in,
                              void* d_out, int out_size, void* d_ws, size_t ws_size,
                              hipStream_t stream) {
    const float* q = (const float*)d_in[0];
    const float* k = (const float*)d_in[1];
    float* out = (float*)d_out;

    QKBmm_74062416052397_kernel<<<dim3(8192), dim3(256), 0, stream>>>(q, k, out);
}